// Round 10
// baseline (272.395 us; speedup 1.0000x reference)
//
#include <hip/hip_runtime.h>

typedef __fp16 h2 __attribute__((ext_vector_type(2)));
typedef __fp16 h8 __attribute__((ext_vector_type(8)));
typedef float f4 __attribute__((ext_vector_type(4)));

namespace {
constexpr int JSTR = 68;          // halves per j-row (64 c + 4 pad) -> 136 B. Keeps LDS at 20096 B
                                  // so 8 blocks/CU fit (tail-wave fix). Bank: stage h2 writes 2-way
                                  // (free); A-frag b128 phases ~4-way (better than JSTR=72's 8-way).
constexpr int JROWS = 40;         // j = d+dz in [0,40): rows 40-47 never feed a valid (dz<9) output.
                                  // wv3's b128 reads at rows 40-47 land in later static LDS (in-bounds
                                  // garbage). Garbage contaminates only C rows m>=8: MFMA C-row m
                                  // depends only on A-row m (lanes l15==m), and wv3's mask
                                  // dz=16+m-l15<9 -> l15>=m+8 -> writes only m<=7. acc re-zeroed
                                  // every round. Safe (verified: R9 passed, absmax 0.25).
constexpr int COLH = JROWS * JSTR;  // 2720 halves = 5440 B per column buffer
}

// R10: spill-free 8 blocks/CU. R9 post-mortem: bounds(256,8) caps VGPR at 64
// but loop-top load issue held lx/ly live across the whole round -> peak ~70+
// -> scratch spills every round (+20 us). Fix: issue next-column loads AFTER
// the MFMA/band-write cluster (before readback). lx/ly now overlap only the
// readback/store phase (~300 cy — covers an L2-resident in2 load; FETCH=22 MB
// shows in2 is L2-hot). Peak liveness ~58-60 < 64. LDS 20096 <= 20480 ->
// true 8 blocks/CU = 32 waves/CU, zero straggler tail (R7/R8 ran 7/CU + a
// 256-block serial tail batch).
//
// Pipeline per column (ONE barrier):
//   1. ds_read A-frags (once), MFMA x 4 pos, band-write acc -> obuf[ci&1]
//   2. issue next-column global loads -> regs        (moved here, VGPR fix)
//   3. readback column ci-1 from obuf[(ci-1)&1] -> global NT stores
//   4. cvt + ds_write staged regs -> colbuf[(ci+1)&1]
//   5. lgkmcnt(0) + s_barrier (NO vmcnt drain — T4)
// Hazard audit (all LDS, all separated by lgkmcnt(0)+barrier):
//   colbuf[(ci+1)&1] write(4,ci)  vs read(1,ci+1)
//   colbuf[ci&1]     read(1,ci)   vs write(4,ci+1)
//   obuf[ci&1]       write(1,ci)  vs read(3,ci+1)
//   obuf[(ci-1)&1]   read(3,ci)   vs write(1,ci+1)
__global__ __launch_bounds__(256, 8) void corr3d_mfma(
    const float* __restrict__ in1, const float* __restrict__ in2,
    float* __restrict__ out)
{
  __shared__ __align__(16) __fp16 colbuf[2][COLH];    // 10880 B
  __shared__ __align__(16) float obuf[2][4 * 288];    // [parity][pos*288+dz*32+d], 9216 B

  const int tid = threadIdx.x;
  // XCD-aware chunked swizzle: blocks sharing in2 are consecutive logical ids;
  // 2048 % 8 == 0 -> bijective, 256-block slab/XCD spans 8 h-rows (R2 evidence:
  // FETCH 303 MB -> 22 MB from this remap family).
  const int blk = ((blockIdx.x & 7) << 8) | (blockIdx.x >> 3);
  const int quarter = blk & 3;            // column-range quarter
  const int w0 = ((blk >> 2) & 7) << 2;   // four w positions: w0 .. w0+3
  const int h = (blk >> 5) & 31;
  const int b = blk >> 10;
  const int ciLo = quarter * 27;
  const int ciHi = ciLo + 27;             // 108 columns (9 hc x 12 wc) split x4

  const int lane = tid & 63;
  const int wv = tid >> 6;  // wave 0..3 = D-tiles (T0,s0),(T1,s0),(T1,s1),(T2,s1)
  const int jb = (wv == 0) ? 0 : (wv == 3) ? 32 : 16;  // A-tile j base
  const int db = (wv >= 2) ? 16 : 0;                   // d-strip base
  const int l15 = lane & 15;
  const int lhi = lane >> 4;

  const float* in1b = in1 + ((size_t)b << 21);
  const float* in2b = in2 + ((size_t)b << 21);

  // zero halo rows of both column buffers (j<4, j>=36): written once, never touched again
  for (int i = tid; i < 576; i += 256) {
    const int bu = i / 288;
    const int r = i - bu * 288;
    const int jrow = r / 36;
    const int cc = r - jrow * 36;
    const int j = (jrow < 4) ? jrow : jrow + 32;  // rows 0-3, 36-39
    h2 z = {(__fp16)0.f, (__fp16)0.f};
    *(h2*)&colbuf[bu][j * JSTR + cc * 2] = z;
  }

  // staging role: d = tid&31 (coalesced), c-quad = tid>>5
  const int sd = tid & 31;
  const int scq = tid >> 5;

  auto stage = [&](const float* src, bool valid, __fp16* dst) {
#pragma unroll
    for (int it = 0; it < 4; ++it) {
      const int cp = scq + (it << 3);  // c-pair 0..31
      h2 v = {(__fp16)0.f, (__fp16)0.f};
      if (valid) {
        const float x = src[((size_t)(2 * cp) << 15) + sd];
        const float y = src[((size_t)(2 * cp + 1) << 15) + sd];
        v = __builtin_amdgcn_cvt_pkrtz(x, y);
      }
      *(h2*)&dst[(4 + sd) * JSTR + 2 * cp] = v;  // [j=4+d][c] layout, rows 4..35
    }
  };

  // ---- prologue: in1 B-operand fragments for all 4 positions (static bfr indices)
  h8 bfr[4][2];
#pragma unroll
  for (int pos = 0; pos < 4; ++pos) {
    __syncthreads();
    stage(in1b + (h << 10) + ((w0 + pos) << 5), true, colbuf[0]);
    __syncthreads();
#pragma unroll
    for (int ch = 0; ch < 2; ++ch)
      bfr[pos][ch] =
          *(const h8*)&colbuf[0][(4 + db + l15) * JSTR + ch * 32 + (lhi << 3)];
  }
  __syncthreads();
  // stage first in2 column (ciLo) into colbuf[ciLo&1]
  {
    const int hcn = ciLo / 12;
    const int wcn = ciLo - hcn * 12;
    const int hp = h - 4 + hcn, wp = w0 - 4 + wcn;
    const bool valid = ((unsigned)hp < 32u) && ((unsigned)wp < 32u);
    stage(in2b + (hp << 10) + (wp << 5), valid, colbuf[ciLo & 1]);
  }
  __syncthreads();

  // band-write constants: m=(lhi*4+r), dz = jb+m-db-l15 = mr+r; off = dz*32+db+l15
  const int mr = jb - db + (lhi << 2) - l15;
  const int dzb = db + l15;

  // ---- main loop over this block's 27 columns, ONE barrier per column
  for (int ci = ciLo; ci < ciHi; ++ci) {
    // (1) compute column ci for all 4 positions, band-write into obuf[ci&1]
    const int hc = ci / 12;
    const int wc = ci - hc * 12;

    const __fp16* cb = colbuf[ci & 1];
    float* ob = obuf[ci & 1];
    const h8 a0 = *(const h8*)&cb[(jb + l15) * JSTR + (lhi << 3)];
    const h8 a1 = *(const h8*)&cb[(jb + l15) * JSTR + 32 + (lhi << 3)];
#pragma unroll
    for (int pos = 0; pos < 4; ++pos) {
      if ((unsigned)(wc - pos) <= 8u) {  // dx = wc - pos in [0,9)
        f4 acc = {0.f, 0.f, 0.f, 0.f};
        acc = __builtin_amdgcn_mfma_f32_16x16x32_f16(a0, bfr[pos][0], acc, 0, 0, 0);
        acc = __builtin_amdgcn_mfma_f32_16x16x32_f16(a1, bfr[pos][1], acc, 0, 0, 0);
#pragma unroll
        for (int r = 0; r < 4; ++r) {
          const int dz = mr + r;
          if ((unsigned)dz < 9u) ob[pos * 288 + dz * 32 + dzb] = acc[r];
        }
      }
    }

    // (2) issue next-column loads into registers (consumed at step 4).
    // Placed AFTER the MFMA cluster so lx/ly don't overlap a0/a1/acc liveness
    // (VGPR cap 64 at 8 waves/SIMD — R9 spilled with loop-top placement).
    float lx[4], ly[4];
    bool nvalid = false;
    if (ci + 1 < ciHi) {
      const int cn = ci + 1;
      const int hcn = cn / 12;
      const int wcn = cn - hcn * 12;
      const int hp = h - 4 + hcn;
      const int wp = w0 - 4 + wcn;
      nvalid = ((unsigned)hp < 32u) && ((unsigned)wp < 32u);
      if (nvalid) {
        const float* src = in2b + (hp << 10) + (wp << 5);
#pragma unroll
        for (int it = 0; it < 4; ++it) {
          const int cp = scq + (it << 3);
          lx[it] = src[((size_t)(2 * cp) << 15) + sd];
          ly[it] = src[((size_t)(2 * cp + 1) << 15) + sd];
        }
      }
    }

    // (3) readback column ci-1 from obuf[(ci-1)&1]: 288 slots over 256 threads
    if (ci > ciLo) {
      const int cprev = ci - 1;
      const int hcp = cprev / 12;
      const int wcp = cprev - hcp * 12;
      const float* op = obuf[cprev & 1];
      for (int s = tid; s < 288; s += 256) {
        const int pos = s / 72;
        const int rr = s - pos * 72;
        const int dz = rr >> 3;
        const int q = rr & 7;
        if ((unsigned)(wcp - pos) <= 8u) {
          const f4 v = *(const f4*)&op[pos * 288 + dz * 32 + (q << 2)];
          const size_t chn = (size_t)(b * 729 + (hcp * 9 + (wcp - pos)) * 9 + dz);
          f4* dstp = (f4*)(out + (chn << 15) + (h << 10) + ((w0 + pos) << 5) + (q << 2));
          __builtin_nontemporal_store(v, dstp);
        }
      }
    }

    // (4) write staged column ci+1 into colbuf[(ci+1)&1] (compiler-inserted
    // vmcnt wait on lx/ly lands here; load latency hidden under step 3)
    if (ci + 1 < ciHi) {
#pragma unroll
      for (int it = 0; it < 4; ++it) {
        const int cp = scq + (it << 3);
        h2 v = {(__fp16)0.f, (__fp16)0.f};
        if (nvalid) v = __builtin_amdgcn_cvt_pkrtz(lx[it], ly[it]);
        *(h2*)&colbuf[(ci + 1) & 1][(4 + sd) * JSTR + 2 * cp] = v;
      }
    }

    // (5) T4 counted-drain barrier: order LDS only; leave NT stores and any
    // in-flight global loads pipelining across rounds. sched_barrier(0) pins
    // the preceding ds ops to this side of the asm (guide rule #18).
    __builtin_amdgcn_sched_barrier(0);
    asm volatile("s_waitcnt lgkmcnt(0)" ::: "memory");
    __builtin_amdgcn_s_barrier();
    __builtin_amdgcn_sched_barrier(0);
  }

  // ---- epilogue: readback this range's last column
  {
    const int cl = ciHi - 1;
    const int hcp = cl / 12;
    const int wcp = cl - hcp * 12;
    const float* op = obuf[cl & 1];
    for (int s = tid; s < 288; s += 256) {
      const int pos = s / 72;
      const int rr = s - pos * 72;
      const int dz = rr >> 3;
      const int q = rr & 7;
      if ((unsigned)(wcp - pos) <= 8u) {
        const f4 v = *(const f4*)&op[pos * 288 + dz * 32 + (q << 2)];
        const size_t chn = (size_t)(b * 729 + (hcp * 9 + (wcp - pos)) * 9 + dz);
        f4* dstp = (f4*)(out + (chn << 15) + (h << 10) + ((w0 + pos) << 5) + (q << 2));
        __builtin_nontemporal_store(v, dstp);
      }
    }
  }
}

extern "C" void kernel_launch(void* const* d_in, const int* in_sizes, int n_in,
                              void* d_out, int out_size, void* d_ws, size_t ws_size,
                              hipStream_t stream) {
  const float* in1 = (const float*)d_in[0];
  const float* in2 = (const float*)d_in[1];
  float* out = (float*)d_out;
  corr3d_mfma<<<dim3(2048), dim3(256), 0, stream>>>(in1, in2, out);
}

// Round 11
// 259.100 us; speedup vs baseline: 1.0513x; 1.0513x over previous
//
#include <hip/hip_runtime.h>

typedef __fp16 h2 __attribute__((ext_vector_type(2)));
typedef __fp16 h8 __attribute__((ext_vector_type(8)));
typedef float f4 __attribute__((ext_vector_type(4)));

namespace {
constexpr int JSTR = 72;          // halves per j-row (64 c + 8 pad) -> 144 B (R7-proven; JSTR=68+bounds8
                                  // regressed ~+24 us in R9/R10: VGPR-64 cap spills with bfr[4][2]).
constexpr int JROWS = 40;         // j = d+dz in [0,40): rows 40-47 never feed a valid (dz<9) output.
                                  // wv3's b128 reads at rows 40-47 read adjacent static LDS (finite
                                  // garbage), contaminating only C rows m>=8, which the dz-mask never
                                  // writes (wv3: dz=16+m-l15<9 -> l15>=m+8 -> m<=7; MFMA C-row m depends
                                  // only on A-row m, held by lanes l15==m). Verified: R7 passed, 0.25.
constexpr int COLH = JROWS * JSTR;  // 2880 halves = 5760 B per column buffer
}

// R11 = exact R7 kernel (best measured: 248.4 us harness) + UNEVEN chunk split.
// R7/R8 ran 7 blocks/CU resident with 8 blocks/CU of work in EQUAL 27-round
// chunks: all 7 residents finish simultaneously, then the 8th runs on a nearly
// empty CU (synchronized-finish tail, ~27 low-occupancy rounds). Fix: split each
// tile's 108 columns as 31/31/31/15. Shorts drain early and backfill -> block
// finishes stagger -> makespan approaches total-work/7-residency (~31 round-
// times) instead of 27+tail (~43). Work conserved; structure untouched.
//
// Pipeline per column (ONE barrier, from R4):
//   1. issue next-column global loads -> regs        (T14 issue-early)
//   2. ds_read A-frags (once), MFMA x 4 pos
//   3. band-write acc -> obuf[ci&1]                  (obuf double-buffered)
//   4. readback column ci-1 from obuf[(ci-1)&1] -> global NT stores
//   5. cvt + ds_write staged regs -> colbuf[(ci+1)&1] (T14 write-late)
//   6. __syncthreads
__global__ __launch_bounds__(256, 7) void corr3d_mfma(
    const float* __restrict__ in1, const float* __restrict__ in2,
    float* __restrict__ out)
{
  __shared__ __align__(16) __fp16 colbuf[2][COLH];    // 11520 B
  __shared__ __align__(16) float obuf[2][4 * 288];    // [parity][pos*288+dz*32+d], 9216 B

  const int tid = threadIdx.x;
  // XCD-aware chunked swizzle: blocks sharing in2 are consecutive logical ids;
  // 2048 % 8 == 0 -> bijective, 256-block slab/XCD spans 8 h-rows (R2 evidence:
  // FETCH 303 MB -> 22 MB from this remap family).
  const int blk = ((blockIdx.x & 7) << 8) | (blockIdx.x >> 3);
  const int quarter = blk & 3;            // column-range chunk
  const int w0 = ((blk >> 2) & 7) << 2;   // four w positions: w0 .. w0+3
  const int h = (blk >> 5) & 31;
  const int b = blk >> 10;
  // Uneven split of the 108 columns (9 hc x 12 wc): 31/31/31/15.
  const int ciLo = quarter * 31;
  const int ciHi = (quarter == 3) ? 108 : ciLo + 31;

  const int lane = tid & 63;
  const int wv = tid >> 6;  // wave 0..3 = D-tiles (T0,s0),(T1,s0),(T1,s1),(T2,s1)
  const int jb = (wv == 0) ? 0 : (wv == 3) ? 32 : 16;  // A-tile j base
  const int db = (wv >= 2) ? 16 : 0;                   // d-strip base
  const int l15 = lane & 15;
  const int lhi = lane >> 4;

  const float* in1b = in1 + ((size_t)b << 21);
  const float* in2b = in2 + ((size_t)b << 21);

  // zero halo rows of both column buffers (j<4, j>=36): written once, never touched again
  for (int i = tid; i < 576; i += 256) {
    const int bu = i / 288;
    const int r = i - bu * 288;
    const int jrow = r / 36;
    const int cc = r - jrow * 36;
    const int j = (jrow < 4) ? jrow : jrow + 32;  // rows 0-3, 36-39
    h2 z = {(__fp16)0.f, (__fp16)0.f};
    *(h2*)&colbuf[bu][j * JSTR + cc * 2] = z;
  }

  // staging role: d = tid&31 (coalesced), c-quad = tid>>5
  const int sd = tid & 31;
  const int scq = tid >> 5;

  auto stage = [&](const float* src, bool valid, __fp16* dst) {
#pragma unroll
    for (int it = 0; it < 4; ++it) {
      const int cp = scq + (it << 3);  // c-pair 0..31
      h2 v = {(__fp16)0.f, (__fp16)0.f};
      if (valid) {
        const float x = src[((size_t)(2 * cp) << 15) + sd];
        const float y = src[((size_t)(2 * cp + 1) << 15) + sd];
        v = __builtin_amdgcn_cvt_pkrtz(x, y);
      }
      *(h2*)&dst[(4 + sd) * JSTR + 2 * cp] = v;  // [j=4+d][c] layout, rows 4..35
    }
  };

  // ---- prologue: in1 B-operand fragments for all 4 positions (static bfr indices)
  h8 bfr[4][2];
#pragma unroll
  for (int pos = 0; pos < 4; ++pos) {
    __syncthreads();
    stage(in1b + (h << 10) + ((w0 + pos) << 5), true, colbuf[0]);
    __syncthreads();
#pragma unroll
    for (int ch = 0; ch < 2; ++ch)
      bfr[pos][ch] =
          *(const h8*)&colbuf[0][(4 + db + l15) * JSTR + ch * 32 + (lhi << 3)];
  }
  __syncthreads();
  // stage first in2 column (ciLo) into colbuf[ciLo&1]
  {
    const int hcn = ciLo / 12;
    const int wcn = ciLo - hcn * 12;
    const int hp = h - 4 + hcn, wp = w0 - 4 + wcn;
    const bool valid = ((unsigned)hp < 32u) && ((unsigned)wp < 32u);
    stage(in2b + (hp << 10) + (wp << 5), valid, colbuf[ciLo & 1]);
  }
  __syncthreads();

  // band-write constants: m=(lhi*4+r), dz = jb+m-db-l15 = mr+r; off = dz*32+db+l15
  const int mr = jb - db + (lhi << 2) - l15;
  const int dzb = db + l15;

  // ---- main loop over this block's columns, ONE barrier per column
  for (int ci = ciLo; ci < ciHi; ++ci) {
    // (1) issue next-column loads into registers (consumed at step 5)
    float lx[4], ly[4];
    bool nvalid = false;
    if (ci + 1 < ciHi) {
      const int cn = ci + 1;
      const int hcn = cn / 12;
      const int wcn = cn - hcn * 12;
      const int hp = h - 4 + hcn;
      const int wp = w0 - 4 + wcn;
      nvalid = ((unsigned)hp < 32u) && ((unsigned)wp < 32u);
      if (nvalid) {
        const float* src = in2b + (hp << 10) + (wp << 5);
#pragma unroll
        for (int it = 0; it < 4; ++it) {
          const int cp = scq + (it << 3);
          lx[it] = src[((size_t)(2 * cp) << 15) + sd];
          ly[it] = src[((size_t)(2 * cp + 1) << 15) + sd];
        }
      }
    }

    // (2,3) compute column ci for all 4 positions, band-write into obuf[ci&1]
    const int hc = ci / 12;
    const int wc = ci - hc * 12;

    const __fp16* cb = colbuf[ci & 1];
    float* ob = obuf[ci & 1];
    const h8 a0 = *(const h8*)&cb[(jb + l15) * JSTR + (lhi << 3)];
    const h8 a1 = *(const h8*)&cb[(jb + l15) * JSTR + 32 + (lhi << 3)];
#pragma unroll
    for (int pos = 0; pos < 4; ++pos) {
      if ((unsigned)(wc - pos) <= 8u) {  // dx = wc - pos in [0,9)
        f4 acc = {0.f, 0.f, 0.f, 0.f};
        acc = __builtin_amdgcn_mfma_f32_16x16x32_f16(a0, bfr[pos][0], acc, 0, 0, 0);
        acc = __builtin_amdgcn_mfma_f32_16x16x32_f16(a1, bfr[pos][1], acc, 0, 0, 0);
#pragma unroll
        for (int r = 0; r < 4; ++r) {
          const int dz = mr + r;
          if ((unsigned)dz < 9u) ob[pos * 288 + dz * 32 + dzb] = acc[r];
        }
      }
    }

    // (4) readback column ci-1 from obuf[(ci-1)&1]: 288 slots over 256 threads
    if (ci > ciLo) {
      const int cprev = ci - 1;
      const int hcp = cprev / 12;
      const int wcp = cprev - hcp * 12;
      const float* op = obuf[cprev & 1];
      for (int s = tid; s < 288; s += 256) {
        const int pos = s / 72;
        const int rr = s - pos * 72;
        const int dz = rr >> 3;
        const int q = rr & 7;
        if ((unsigned)(wcp - pos) <= 8u) {
          const f4 v = *(const f4*)&op[pos * 288 + dz * 32 + (q << 2)];
          const size_t chn = (size_t)(b * 729 + (hcp * 9 + (wcp - pos)) * 9 + dz);
          f4* dstp = (f4*)(out + (chn << 15) + (h << 10) + ((w0 + pos) << 5) + (q << 2));
          __builtin_nontemporal_store(v, dstp);
        }
      }
    }

    // (5) write staged column ci+1 into colbuf[(ci+1)&1] (compiler-inserted
    // vmcnt wait on lx/ly lands here; load latency hidden under steps 2-4)
    if (ci + 1 < ciHi) {
#pragma unroll
      for (int it = 0; it < 4; ++it) {
        const int cp = scq + (it << 3);
        h2 v = {(__fp16)0.f, (__fp16)0.f};
        if (nvalid) v = __builtin_amdgcn_cvt_pkrtz(lx[it], ly[it]);
        *(h2*)&colbuf[(ci + 1) & 1][(4 + sd) * JSTR + 2 * cp] = v;
      }
    }

    __syncthreads();  // the single per-column barrier
  }

  // ---- epilogue: readback this range's last column
  {
    const int cl = ciHi - 1;
    const int hcp = cl / 12;
    const int wcp = cl - hcp * 12;
    const float* op = obuf[cl & 1];
    for (int s = tid; s < 288; s += 256) {
      const int pos = s / 72;
      const int rr = s - pos * 72;
      const int dz = rr >> 3;
      const int q = rr & 7;
      if ((unsigned)(wcp - pos) <= 8u) {
        const f4 v = *(const f4*)&op[pos * 288 + dz * 32 + (q << 2)];
        const size_t chn = (size_t)(b * 729 + (hcp * 9 + (wcp - pos)) * 9 + dz);
        f4* dstp = (f4*)(out + (chn << 15) + (h << 10) + ((w0 + pos) << 5) + (q << 2));
        __builtin_nontemporal_store(v, dstp);
      }
    }
  }
}

extern "C" void kernel_launch(void* const* d_in, const int* in_sizes, int n_in,
                              void* d_out, int out_size, void* d_ws, size_t ws_size,
                              hipStream_t stream) {
  const float* in1 = (const float*)d_in[0];
  const float* in2 = (const float*)d_in[1];
  float* out = (float*)d_out;
  corr3d_mfma<<<dim3(2048), dim3(256), 0, stream>>>(in1, in2, out);
}

// Round 13
// 249.506 us; speedup vs baseline: 1.0917x; 1.0385x over previous
//
#include <hip/hip_runtime.h>

typedef __fp16 h2 __attribute__((ext_vector_type(2)));
typedef __fp16 h4 __attribute__((ext_vector_type(4)));
typedef __fp16 h8 __attribute__((ext_vector_type(8)));
typedef float f4 __attribute__((ext_vector_type(4)));

namespace {
constexpr int JSTR = 72;          // halves per j-row (64 c + 8 pad) -> 144 B (R7-proven)
constexpr int JROWS = 40;         // j = d+dz in [0,40): rows 40-47 never feed a valid (dz<9) output.
                                  // wv3's b128 reads at rows 40-47 read adjacent static LDS (finite
                                  // garbage), contaminating only C rows m>=8, which the dz-mask never
                                  // writes (wv3: dz=16+m-l15<9 -> l15>=m+8 -> m<=7). Verified R7, 0.25.
constexpr int COLH = JROWS * JSTR;  // 2880 halves = 5760 B per column buffer
constexpr int OSTR = 36;          // obuf row stride in floats: 32 d + 4 pad = 144 B. At stride 32
                                  // (128 B = exact bank wrap) the readback's 8 dz-groups all hit the
                                  // same bank quad -> 8-way conflict (~280 cy/block-round, matches the
                                  // 1.3e7 SQ_LDS_BANK_CONFLICT). Stride 36 spreads dz-groups evenly.
constexpr int OPOS = 9 * OSTR;    // 324 floats per position
}

// R13 = R12 resubmit (container-infra failure, not a kernel failure).
// R12 = R7 (best: 248.4) + two DS-cycle cuts. Cycle model: one LDS pipe/CU at
// ~900 cy/block-round x 8 blocks x 31 rounds = ~80 us ~= measured kernel time
// -> LDS-pipe-bound. This explains the R8/R9/R10/R11 nulls (none cut DS work).
// Cuts: (1) obuf row pad 32->36 floats kills the 8-way readback conflict;
// (2) stage ds_writes b32->b64 via cp=4*scq+it thread->c remap (adjacent pairs).
//
// Pipeline per column (ONE barrier, from R4):
//   1. issue next-column global loads -> regs        (T14 issue-early)
//   2. ds_read A-frags (once), MFMA x 4 pos
//   3. band-write acc -> obuf[ci&1]                  (obuf double-buffered)
//   4. readback column ci-1 from obuf[(ci-1)&1] -> global NT stores
//   5. cvt + ds_write staged regs -> colbuf[(ci+1)&1] (T14 write-late)
//   6. __syncthreads
__global__ __launch_bounds__(256, 7) void corr3d_mfma(
    const float* __restrict__ in1, const float* __restrict__ in2,
    float* __restrict__ out)
{
  __shared__ __align__(16) __fp16 colbuf[2][COLH];      // 11520 B
  __shared__ __align__(16) float obuf[2][4 * OPOS];     // [parity][pos*324+dz*36+d], 10368 B

  const int tid = threadIdx.x;
  // XCD-aware chunked swizzle: blocks sharing in2 are consecutive logical ids;
  // 2048 % 8 == 0 -> bijective, 256-block slab/XCD spans 8 h-rows (R2 evidence:
  // FETCH 303 MB -> 22 MB from this remap family).
  const int blk = ((blockIdx.x & 7) << 8) | (blockIdx.x >> 3);
  const int quarter = blk & 3;            // column-range quarter (equal 27s: R11's
                                          // uneven 31/31/31/15 split regressed +11 us)
  const int w0 = ((blk >> 2) & 7) << 2;   // four w positions: w0 .. w0+3
  const int h = (blk >> 5) & 31;
  const int b = blk >> 10;
  const int ciLo = quarter * 27;
  const int ciHi = ciLo + 27;             // 108 columns (9 hc x 12 wc) split x4

  const int lane = tid & 63;
  const int wv = tid >> 6;  // wave 0..3 = D-tiles (T0,s0),(T1,s0),(T1,s1),(T2,s1)
  const int jb = (wv == 0) ? 0 : (wv == 3) ? 32 : 16;  // A-tile j base
  const int db = (wv >= 2) ? 16 : 0;                   // d-strip base
  const int l15 = lane & 15;
  const int lhi = lane >> 4;

  const float* in1b = in1 + ((size_t)b << 21);
  const float* in2b = in2 + ((size_t)b << 21);

  // zero halo rows of both column buffers (j<4, j>=36): written once, never touched again
  for (int i = tid; i < 576; i += 256) {
    const int bu = i / 288;
    const int r = i - bu * 288;
    const int jrow = r / 36;
    const int cc = r - jrow * 36;
    const int j = (jrow < 4) ? jrow : jrow + 32;  // rows 0-3, 36-39
    h2 z = {(__fp16)0.f, (__fp16)0.f};
    *(h2*)&colbuf[bu][j * JSTR + cc * 2] = z;
  }

  // staging role: d = tid&31 (coalesced), c-group = tid>>5; thread owns c-pairs
  // cp = 4*scq + it (adjacent pairs -> b64 LDS writes)
  const int sd = tid & 31;
  const int scq = tid >> 5;

  auto stage = [&](const float* src, bool valid, __fp16* dst) {
#pragma unroll
    for (int itp = 0; itp < 2; ++itp) {
      const int cp0 = (scq << 2) + (itp << 1);  // c-pairs cp0, cp0+1
      h4 v = {(__fp16)0.f, (__fp16)0.f, (__fp16)0.f, (__fp16)0.f};
      if (valid) {
        const float x0 = src[((size_t)(2 * cp0) << 15) + sd];
        const float y0 = src[((size_t)(2 * cp0 + 1) << 15) + sd];
        const float x1 = src[((size_t)(2 * cp0 + 2) << 15) + sd];
        const float y1 = src[((size_t)(2 * cp0 + 3) << 15) + sd];
        const h2 p0 = __builtin_amdgcn_cvt_pkrtz(x0, y0);
        const h2 p1 = __builtin_amdgcn_cvt_pkrtz(x1, y1);
        v[0] = p0[0]; v[1] = p0[1]; v[2] = p1[0]; v[3] = p1[1];
      }
      *(h4*)&dst[(4 + sd) * JSTR + (cp0 << 1)] = v;  // b64, 8B-aligned
    }
  };

  // ---- prologue: in1 B-operand fragments for all 4 positions (static bfr indices)
  h8 bfr[4][2];
#pragma unroll
  for (int pos = 0; pos < 4; ++pos) {
    __syncthreads();
    stage(in1b + (h << 10) + ((w0 + pos) << 5), true, colbuf[0]);
    __syncthreads();
#pragma unroll
    for (int ch = 0; ch < 2; ++ch)
      bfr[pos][ch] =
          *(const h8*)&colbuf[0][(4 + db + l15) * JSTR + ch * 32 + (lhi << 3)];
  }
  __syncthreads();
  // stage first in2 column (ciLo) into colbuf[ciLo&1]
  {
    const int hcn = ciLo / 12;
    const int wcn = ciLo - hcn * 12;
    const int hp = h - 4 + hcn, wp = w0 - 4 + wcn;
    const bool valid = ((unsigned)hp < 32u) && ((unsigned)wp < 32u);
    stage(in2b + (hp << 10) + (wp << 5), valid, colbuf[ciLo & 1]);
  }
  __syncthreads();

  // band-write constants: m=(lhi*4+r), dz = jb+m-db-l15 = mr+r; off = dz*36+db+l15
  const int mr = jb - db + (lhi << 2) - l15;
  const int dzb = db + l15;

  // ---- main loop over this block's 27 columns, ONE barrier per column
  for (int ci = ciLo; ci < ciHi; ++ci) {
    // (1) issue next-column loads into registers (consumed at step 5)
    float lx[4], ly[4];
    bool nvalid = false;
    if (ci + 1 < ciHi) {
      const int cn = ci + 1;
      const int hcn = cn / 12;
      const int wcn = cn - hcn * 12;
      const int hp = h - 4 + hcn;
      const int wp = w0 - 4 + wcn;
      nvalid = ((unsigned)hp < 32u) && ((unsigned)wp < 32u);
      if (nvalid) {
        const float* src = in2b + (hp << 10) + (wp << 5);
#pragma unroll
        for (int it = 0; it < 4; ++it) {
          const int cp = (scq << 2) + it;
          lx[it] = src[((size_t)(2 * cp) << 15) + sd];
          ly[it] = src[((size_t)(2 * cp + 1) << 15) + sd];
        }
      }
    }

    // (2,3) compute column ci for all 4 positions, band-write into obuf[ci&1]
    const int hc = ci / 12;
    const int wc = ci - hc * 12;

    const __fp16* cb = colbuf[ci & 1];
    float* ob = obuf[ci & 1];
    const h8 a0 = *(const h8*)&cb[(jb + l15) * JSTR + (lhi << 3)];
    const h8 a1 = *(const h8*)&cb[(jb + l15) * JSTR + 32 + (lhi << 3)];
#pragma unroll
    for (int pos = 0; pos < 4; ++pos) {
      if ((unsigned)(wc - pos) <= 8u) {  // dx = wc - pos in [0,9)
        f4 acc = {0.f, 0.f, 0.f, 0.f};
        acc = __builtin_amdgcn_mfma_f32_16x16x32_f16(a0, bfr[pos][0], acc, 0, 0, 0);
        acc = __builtin_amdgcn_mfma_f32_16x16x32_f16(a1, bfr[pos][1], acc, 0, 0, 0);
#pragma unroll
        for (int r = 0; r < 4; ++r) {
          const int dz = mr + r;
          if ((unsigned)dz < 9u) ob[pos * OPOS + dz * OSTR + dzb] = acc[r];
        }
      }
    }

    // (4) readback column ci-1 from obuf[(ci-1)&1]: 288 f4 slots over 256 threads
    if (ci > ciLo) {
      const int cprev = ci - 1;
      const int hcp = cprev / 12;
      const int wcp = cprev - hcp * 12;
      const float* op = obuf[cprev & 1];
      for (int s = tid; s < 288; s += 256) {
        const int pos = s / 72;
        const int rr = s - pos * 72;
        const int dz = rr >> 3;
        const int q = rr & 7;
        if ((unsigned)(wcp - pos) <= 8u) {
          const f4 v = *(const f4*)&op[pos * OPOS + dz * OSTR + (q << 2)];
          const size_t chn = (size_t)(b * 729 + (hcp * 9 + (wcp - pos)) * 9 + dz);
          f4* dstp = (f4*)(out + (chn << 15) + (h << 10) + ((w0 + pos) << 5) + (q << 2));
          __builtin_nontemporal_store(v, dstp);
        }
      }
    }

    // (5) write staged column ci+1 into colbuf[(ci+1)&1] as b64 (compiler vmcnt
    // wait on lx/ly lands here; load latency hidden under steps 2-4)
    if (ci + 1 < ciHi) {
#pragma unroll
      for (int itp = 0; itp < 2; ++itp) {
        const int cp0 = (scq << 2) + (itp << 1);
        h4 v = {(__fp16)0.f, (__fp16)0.f, (__fp16)0.f, (__fp16)0.f};
        if (nvalid) {
          const h2 p0 = __builtin_amdgcn_cvt_pkrtz(lx[2 * itp], ly[2 * itp]);
          const h2 p1 = __builtin_amdgcn_cvt_pkrtz(lx[2 * itp + 1], ly[2 * itp + 1]);
          v[0] = p0[0]; v[1] = p0[1]; v[2] = p1[0]; v[3] = p1[1];
        }
        *(h4*)&colbuf[(ci + 1) & 1][(4 + sd) * JSTR + (cp0 << 1)] = v;
      }
    }

    __syncthreads();  // the single per-column barrier
  }

  // ---- epilogue: readback this range's last column
  {
    const int cl = ciHi - 1;
    const int hcp = cl / 12;
    const int wcp = cl - hcp * 12;
    const float* op = obuf[cl & 1];
    for (int s = tid; s < 288; s += 256) {
      const int pos = s / 72;
      const int rr = s - pos * 72;
      const int dz = rr >> 3;
      const int q = rr & 7;
      if ((unsigned)(wcp - pos) <= 8u) {
        const f4 v = *(const f4*)&op[pos * OPOS + dz * OSTR + (q << 2)];
        const size_t chn = (size_t)(b * 729 + (hcp * 9 + (wcp - pos)) * 9 + dz);
        f4* dstp = (f4*)(out + (chn << 15) + (h << 10) + ((w0 + pos) << 5) + (q << 2));
        __builtin_nontemporal_store(v, dstp);
      }
    }
  }
}

extern "C" void kernel_launch(void* const* d_in, const int* in_sizes, int n_in,
                              void* d_out, int out_size, void* d_ws, size_t ws_size,
                              hipStream_t stream) {
  const float* in1 = (const float*)d_in[0];
  const float* in2 = (const float*)d_in[1];
  float* out = (float*)d_out;
  corr3d_mfma<<<dim3(2048), dim3(256), 0, stream>>>(in1, in2, out);
}